// Round 2
// baseline (389.785 us; speedup 1.0000x reference)
//
#include <hip/hip_runtime.h>
#include <hip/hip_bf16.h>
#include <math.h>

#define F_IN  32
#define F_HID 32
#define F_OUT 16

// ---------------- degree ----------------
__global__ void k_init_deg(int* __restrict__ deg, int n) {
    int i = blockIdx.x * 256 + threadIdx.x;
    if (i < n) deg[i] = 1;  // self-loop
}

__global__ void k_count_deg(const int* __restrict__ ei, int ne, int* __restrict__ deg) {
    int e = blockIdx.x * 256 + threadIdx.x;
    if (e < ne) atomicAdd(&deg[ei[ne + e]], 1);  // dst
}

// ---------------- scan (exclusive, over deg[i]-1) + dinv ----------------
// chunk = 1024 elems/block (256 thr x 4)
__global__ void k_scan1(const int* __restrict__ deg, float* __restrict__ dinv,
                        int* __restrict__ bsum, int n) {
    __shared__ int sh[256];
    int t = threadIdx.x;
    int base = blockIdx.x * 1024 + t * 4;
    int s = 0;
    #pragma unroll
    for (int j = 0; j < 4; ++j) {
        int i = base + j;
        if (i < n) {
            int d = deg[i];
            dinv[i] = rsqrtf((float)d);
            s += d - 1;
        }
    }
    sh[t] = s; __syncthreads();
    for (int o = 128; o > 0; o >>= 1) {
        if (t < o) sh[t] += sh[t + o];
        __syncthreads();
    }
    if (t == 0) bsum[blockIdx.x] = sh[0];
}

__global__ void k_scan2(const int* __restrict__ bsum, int* __restrict__ boff, int nblk) {
    __shared__ int sh[128];
    int t = threadIdx.x;
    int v = (t < nblk) ? bsum[t] : 0;
    sh[t] = v; __syncthreads();
    for (int o = 1; o < 128; o <<= 1) {
        int u = (t >= o) ? sh[t - o] : 0;
        __syncthreads();
        sh[t] += u;
        __syncthreads();
    }
    if (t < nblk) boff[t] = sh[t] - v;  // exclusive
}

__global__ void k_scan3(const int* __restrict__ deg, const int* __restrict__ boff,
                        int* __restrict__ off, int* __restrict__ cur, int n) {
    __shared__ int sh[256];
    int t = threadIdx.x;
    int base = blockIdx.x * 1024 + t * 4;
    int v[4]; int s = 0;
    #pragma unroll
    for (int j = 0; j < 4; ++j) {
        int i = base + j;
        v[j] = (i < n) ? (deg[i] - 1) : 0;
        s += v[j];
    }
    sh[t] = s; __syncthreads();
    int mine = s;
    for (int o = 1; o < 256; o <<= 1) {
        int u = (t >= o) ? sh[t - o] : 0;
        __syncthreads();
        sh[t] += u;
        __syncthreads();
    }
    int run = sh[t] - mine + boff[blockIdx.x];
    #pragma unroll
    for (int j = 0; j < 4; ++j) {
        int i = base + j;
        if (i < n) { off[i] = run; cur[i] = run; run += v[j]; }
    }
}

// ---------------- CSR fill (int atomics only) ----------------
__global__ void k_fill(const int* __restrict__ ei, int ne,
                       int* __restrict__ cur, int* __restrict__ csr) {
    int e = blockIdx.x * 256 + threadIdx.x;
    if (e >= ne) return;
    int d = ei[ne + e];
    int p = atomicAdd(&cur[d], 1);
    csr[p] = ei[e];  // src
}

// ---------------- g1 = (x @ W1) * dinv ----------------
__launch_bounds__(256)
__global__ void k_mm1(const float* __restrict__ x, const float* __restrict__ W1,
                      const float* __restrict__ dinv, float* __restrict__ g1, int n) {
    __shared__ float Ws[F_IN * F_HID];
    __shared__ float xs[8 * F_IN];
    int t = threadIdx.x;
    for (int i = t; i < F_IN * F_HID; i += 256) Ws[i] = W1[i];
    int nl = t >> 5, c = t & 31;
    int node = blockIdx.x * 8 + nl;
    if (node < n) xs[t] = x[(size_t)node * F_IN + c];
    __syncthreads();
    if (node >= n) return;
    float sum = 0.f;
    #pragma unroll
    for (int k = 0; k < F_IN; ++k) sum += xs[nl * F_IN + k] * Ws[k * F_HID + c];
    g1[(size_t)node * F_HID + c] = sum * dinv[node];
}

// ---------------- agg1: h = tanh(dinv*(self + sum_neighbors) + b1) ----------------
// one wave (64 lanes) per node: 32 channels x 2 edge slots
__launch_bounds__(256)
__global__ void k_agg1(const float* __restrict__ g1, const int* __restrict__ csr,
                       const int* __restrict__ off, const int* __restrict__ deg,
                       const float* __restrict__ dinv, const float* __restrict__ b1,
                       float* __restrict__ h, int n) {
    int t = threadIdx.x;
    int wave = t >> 6, lane = t & 63;
    int node = blockIdx.x * 4 + wave;
    if (node >= n) return;
    int c = lane & 31, slot = lane >> 5;  // 2 slots
    int start = off[node], cnt = deg[node] - 1;
    float sum = 0.f;
    for (int k = slot; k < cnt; k += 2) {
        int s = csr[start + k];
        sum += g1[(size_t)s * F_HID + c];
    }
    sum += __shfl_xor(sum, 32);
    sum += g1[(size_t)node * F_HID + c];  // self-loop
    float hv = tanhf(sum * dinv[node] + b1[c]);
    if (lane < 32) h[(size_t)node * F_HID + c] = hv;
}

// ---------------- g2 = (h @ W2) * dinv ----------------
__launch_bounds__(256)
__global__ void k_mm2(const float* __restrict__ h, const float* __restrict__ W2,
                      const float* __restrict__ dinv, float* __restrict__ g2, int n) {
    __shared__ float Ws[F_HID * F_OUT];
    __shared__ float hs[16 * F_HID];
    int t = threadIdx.x;
    for (int i = t; i < F_HID * F_OUT; i += 256) Ws[i] = W2[i];
    int node0 = blockIdx.x * 16;
    for (int i = t; i < 16 * F_HID; i += 256) {
        int nl = i >> 5, k = i & 31;
        int node = node0 + nl;
        hs[i] = (node < n) ? h[(size_t)node * F_HID + k] : 0.f;
    }
    __syncthreads();
    int nl = t >> 4, c = t & 15;
    int node = node0 + nl;
    if (node >= n) return;
    float s = 0.f;
    #pragma unroll
    for (int k = 0; k < F_HID; ++k) s += hs[nl * F_HID + k] * Ws[k * F_OUT + c];
    g2[(size_t)node * F_OUT + c] = s * dinv[node];
}

// ---------------- agg2 + bias + log_softmax ----------------
// one wave per node: 16 channels x 4 edge slots
__launch_bounds__(256)
__global__ void k_agg2(const float* __restrict__ g2, const int* __restrict__ csr,
                       const int* __restrict__ off, const int* __restrict__ deg,
                       const float* __restrict__ dinv, const float* __restrict__ b2,
                       float* __restrict__ out_h, float* __restrict__ out_ls, int n) {
    int t = threadIdx.x;
    int wave = t >> 6, lane = t & 63;
    int node = blockIdx.x * 4 + wave;
    if (node >= n) return;
    int c = lane & 15, slot = lane >> 4;  // 4 slots
    int start = off[node], cnt = deg[node] - 1;
    float sum = 0.f;
    for (int k = slot; k < cnt; k += 4) {
        int s = csr[start + k];
        sum += g2[(size_t)s * F_OUT + c];
    }
    sum += __shfl_xor(sum, 32);
    sum += __shfl_xor(sum, 16);
    sum += g2[(size_t)node * F_OUT + c];  // self-loop
    float v = sum * dinv[node] + b2[c];
    float m = v;
    #pragma unroll
    for (int o = 8; o >= 1; o >>= 1) m = fmaxf(m, __shfl_xor(m, o));
    float e = expf(v - m), S = e;
    #pragma unroll
    for (int o = 8; o >= 1; o >>= 1) S += __shfl_xor(S, o);
    float l = logf(S) + m;
    if (lane < 16) {
        out_h[(size_t)node * F_OUT + c] = v;
        out_ls[(size_t)node * F_OUT + c] = v - l;
    }
}

extern "C" void kernel_launch(void* const* d_in, const int* in_sizes, int n_in,
                              void* d_out, int out_size, void* d_ws, size_t ws_size,
                              hipStream_t stream) {
    const float* x  = (const float*)d_in[0];
    const int*   ei = (const int*)d_in[1];   // [2,E]: [0:E]=src, [E:2E]=dst
    const float* W1 = (const float*)d_in[2];
    const float* b1 = (const float*)d_in[3];
    const float* W2 = (const float*)d_in[4];
    const float* b2 = (const float*)d_in[5];

    int n  = in_sizes[0] / F_IN;
    int ne = in_sizes[1] / 2;
    int nblk = (n + 1023) / 1024;

    float* out_h  = (float*)d_out;
    float* out_ls = out_h + (size_t)n * F_OUT;

    char* p = (char*)d_ws;
    int*   deg  = (int*)p;   p += (size_t)n * sizeof(int);
    float* dinv = (float*)p; p += (size_t)n * sizeof(float);
    int*   off  = (int*)p;   p += (size_t)n * sizeof(int);
    int*   cur  = (int*)p;   p += (size_t)n * sizeof(int);
    int*   bsum = (int*)p;   p += 256 * sizeof(int);
    int*   boff = (int*)p;   p += 256 * sizeof(int);
    int*   csr  = (int*)p;   p += (size_t)ne * sizeof(int);
    float* g1   = (float*)p; p += (size_t)n * F_HID * sizeof(float);
    float* h    = (float*)p; p += (size_t)n * F_HID * sizeof(float);
    float* g2   = g1;  // g1 dead after k_agg1; reuse

    k_init_deg<<<(n + 255) / 256, 256, 0, stream>>>(deg, n);
    k_count_deg<<<(ne + 255) / 256, 256, 0, stream>>>(ei, ne, deg);
    k_scan1<<<nblk, 256, 0, stream>>>(deg, dinv, bsum, n);
    k_scan2<<<1, 128, 0, stream>>>(bsum, boff, nblk);
    k_scan3<<<nblk, 256, 0, stream>>>(deg, boff, off, cur, n);
    k_fill<<<(ne + 255) / 256, 256, 0, stream>>>(ei, ne, cur, csr);

    k_mm1<<<(n + 7) / 8, 256, 0, stream>>>(x, W1, dinv, g1, n);
    k_agg1<<<(n + 3) / 4, 256, 0, stream>>>(g1, csr, off, deg, dinv, b1, h, n);
    k_mm2<<<(n + 15) / 16, 256, 0, stream>>>(h, W2, dinv, g2, n);
    k_agg2<<<(n + 3) / 4, 256, 0, stream>>>(g2, csr, off, deg, dinv, b2, out_h, out_ls, n);
}

// Round 3
// 273.229 us; speedup vs baseline: 1.4266x; 1.4266x over previous
//
#include <hip/hip_runtime.h>
#include <hip/hip_bf16.h>
#include <math.h>
#include <stdint.h>

#define F_IN  32
#define F_HID 32
#define F_OUT 16

// ---------------- degree ----------------
__global__ void k_init_deg(int* __restrict__ deg, int n) {
    int i = blockIdx.x * 256 + threadIdx.x;
    if (i < n) deg[i] = 1;  // self-loop
}

__global__ void k_count_deg(const int* __restrict__ ei, int ne, int* __restrict__ deg) {
    int e = blockIdx.x * 256 + threadIdx.x;
    if (e < ne) atomicAdd(&deg[ei[ne + e]], 1);  // dst
}

__global__ void k_dinv(const int* __restrict__ deg, float* __restrict__ dinv, int n) {
    int i = blockIdx.x * 256 + threadIdx.x;
    if (i < n) dinv[i] = rsqrtf((float)deg[i]);
}

// ---------------- layer 1: g1 = (x @ W1) * dinv, packed f16x2; s1 seeded = g1 ----
__launch_bounds__(256)
__global__ void k_mm1(const float* __restrict__ x, const float* __restrict__ W1,
                      const float* __restrict__ dinv,
                      uint32_t* __restrict__ g1, uint32_t* __restrict__ s1, int n) {
    __shared__ float Ws[F_IN * F_HID];
    __shared__ float xs[8 * F_IN];
    int t = threadIdx.x;
    for (int i = t; i < F_IN * F_HID; i += 256) Ws[i] = W1[i];
    int nl = t >> 5, c = t & 31;
    int node = blockIdx.x * 8 + nl;
    if (node < n) xs[t] = x[(size_t)node * F_IN + c];
    __syncthreads();
    if (node >= n) return;
    float sum = 0.f;
    #pragma unroll
    for (int k = 0; k < F_IN; ++k) sum += xs[nl * F_IN + k] * Ws[k * F_HID + c];
    float gv = sum * dinv[node];
    float hi = __shfl_xor(gv, 1);  // partner channel c^1 (same node)
    if ((c & 1) == 0) {
        union { _Float16 h[2]; uint32_t u; } pk;
        pk.h[0] = (_Float16)gv; pk.h[1] = (_Float16)hi;
        size_t o = (size_t)node * 16 + (c >> 1);
        g1[o] = pk.u;
        s1[o] = pk.u;  // self-loop seed
    }
}

// ---------------- edge scatter layer 1: 16 packed-f16x2 atomics per edge ----
__global__ void k_edge1(const int* __restrict__ ei, int ne,
                        const uint32_t* __restrict__ g, uint32_t* __restrict__ s) {
    long gid = (long)blockIdx.x * 256 + threadIdx.x;
    int e = (int)(gid >> 4), cp = (int)(gid & 15);
    if (e >= ne) return;
    int sn = ei[e], dn = ei[ne + e];
    uint32_t val = g[(size_t)sn * 16 + cp];
    uint64_t addr = (uint64_t)(uintptr_t)(s + (size_t)dn * 16 + cp);
    asm volatile("global_atomic_pk_add_f16 %0, %1, off"
                 :: "v"(addr), "v"(val) : "memory");
}

// ---------------- mid: h = tanh(dinv*s1 + b1); g2 = (h @ W2)*dinv packed; s2 = g2 ----
__launch_bounds__(256)
__global__ void k_mid(const uint32_t* __restrict__ s1, const float* __restrict__ dinv,
                      const float* __restrict__ b1, const float* __restrict__ W2,
                      uint32_t* __restrict__ g2, uint32_t* __restrict__ s2, int n) {
    __shared__ float Ws[F_HID * F_OUT];  // 32x16
    __shared__ float hs[16 * F_HID];     // 16 nodes per block
    int t = threadIdx.x;
    for (int i = t; i < F_HID * F_OUT; i += 256) Ws[i] = W2[i];
    int node0 = blockIdx.x * 16;
    {
        int nl = t >> 4, cp = t & 15;
        int node = node0 + nl;
        float vx = 0.f, vy = 0.f;
        if (node < n) {
            union { uint32_t u; _Float16 h[2]; } pk;
            pk.u = s1[(size_t)node * 16 + cp];
            float di = dinv[node];
            vx = tanhf(di * (float)pk.h[0] + b1[2 * cp]);
            vy = tanhf(di * (float)pk.h[1] + b1[2 * cp + 1]);
        }
        hs[nl * F_HID + 2 * cp]     = vx;
        hs[nl * F_HID + 2 * cp + 1] = vy;
    }
    __syncthreads();
    int nl = t >> 4, c = t & 15;
    int node = node0 + nl;
    if (node >= n) return;
    float s = 0.f;
    #pragma unroll
    for (int k = 0; k < F_HID; ++k) s += hs[nl * F_HID + k] * Ws[k * F_OUT + c];
    float gv = s * dinv[node];
    float hi = __shfl_xor(gv, 1);
    if ((c & 1) == 0) {
        union { _Float16 h[2]; uint32_t u; } pk;
        pk.h[0] = (_Float16)gv; pk.h[1] = (_Float16)hi;
        size_t o = (size_t)node * 8 + (c >> 1);
        g2[o] = pk.u;
        s2[o] = pk.u;  // self-loop seed
    }
}

// ---------------- edge scatter layer 2: 8 packed-f16x2 atomics per edge ----
__global__ void k_edge2(const int* __restrict__ ei, int ne,
                        const uint32_t* __restrict__ g, uint32_t* __restrict__ s) {
    long gid = (long)blockIdx.x * 256 + threadIdx.x;
    int e = (int)(gid >> 3), cp = (int)(gid & 7);
    if (e >= ne) return;
    int sn = ei[e], dn = ei[ne + e];
    uint32_t val = g[(size_t)sn * 8 + cp];
    uint64_t addr = (uint64_t)(uintptr_t)(s + (size_t)dn * 8 + cp);
    asm volatile("global_atomic_pk_add_f16 %0, %1, off"
                 :: "v"(addr), "v"(val) : "memory");
}

// ---------------- finish: out = dinv*s2 + b2 ; log_softmax ----------------
__global__ void k_final(const uint32_t* __restrict__ s2, const float* __restrict__ dinv,
                        const float* __restrict__ b2,
                        float* __restrict__ out_h, float* __restrict__ out_ls, int n) {
    int i = blockIdx.x * 256 + threadIdx.x;
    if (i >= n) return;
    float di = dinv[i];
    float v[F_OUT];
    float m = -INFINITY;
    #pragma unroll
    for (int cp = 0; cp < 8; ++cp) {
        union { uint32_t u; _Float16 h[2]; } pk;
        pk.u = s2[(size_t)i * 8 + cp];
        v[2 * cp]     = di * (float)pk.h[0] + b2[2 * cp];
        v[2 * cp + 1] = di * (float)pk.h[1] + b2[2 * cp + 1];
        m = fmaxf(m, fmaxf(v[2 * cp], v[2 * cp + 1]));
    }
    float sum = 0.f;
    #pragma unroll
    for (int c = 0; c < F_OUT; ++c) sum += expf(v[c] - m);
    float l = logf(sum) + m;
    #pragma unroll
    for (int c = 0; c < F_OUT; ++c) {
        out_h[(size_t)i * F_OUT + c] = v[c];
        out_ls[(size_t)i * F_OUT + c] = v[c] - l;
    }
}

extern "C" void kernel_launch(void* const* d_in, const int* in_sizes, int n_in,
                              void* d_out, int out_size, void* d_ws, size_t ws_size,
                              hipStream_t stream) {
    const float* x  = (const float*)d_in[0];
    const int*   ei = (const int*)d_in[1];   // [2,E]: [0:E]=src, [E:2E]=dst
    const float* W1 = (const float*)d_in[2];
    const float* b1 = (const float*)d_in[3];
    const float* W2 = (const float*)d_in[4];
    const float* b2 = (const float*)d_in[5];

    int n  = in_sizes[0] / F_IN;
    int ne = in_sizes[1] / 2;

    float* out_h  = (float*)d_out;
    float* out_ls = out_h + (size_t)n * F_OUT;

    char* p = (char*)d_ws;
    int*      deg  = (int*)p;      p += (size_t)n * sizeof(int);
    float*    dinv = (float*)p;    p += (size_t)n * sizeof(float);
    uint32_t* g1   = (uint32_t*)p; p += (size_t)n * 16 * sizeof(uint32_t);
    uint32_t* s1   = (uint32_t*)p; p += (size_t)n * 16 * sizeof(uint32_t);
    uint32_t* g2   = (uint32_t*)p; p += (size_t)n * 8 * sizeof(uint32_t);
    uint32_t* s2   = (uint32_t*)p; p += (size_t)n * 8 * sizeof(uint32_t);

    k_init_deg<<<(n + 255) / 256, 256, 0, stream>>>(deg, n);
    k_count_deg<<<(ne + 255) / 256, 256, 0, stream>>>(ei, ne, deg);
    k_dinv<<<(n + 255) / 256, 256, 0, stream>>>(deg, dinv, n);

    k_mm1<<<(n + 7) / 8, 256, 0, stream>>>(x, W1, dinv, g1, s1, n);

    long tot1 = (long)ne * 16;
    k_edge1<<<(int)((tot1 + 255) / 256), 256, 0, stream>>>(ei, ne, g1, s1);

    k_mid<<<(n + 15) / 16, 256, 0, stream>>>(s1, dinv, b1, W2, g2, s2, n);

    long tot2 = (long)ne * 8;
    k_edge2<<<(int)((tot2 + 255) / 256), 256, 0, stream>>>(ei, ne, g2, s2);

    k_final<<<(n + 255) / 256, 256, 0, stream>>>(s2, dinv, b2, out_h, out_ls, n);
}